// Round 1
// baseline (159.270 us; speedup 1.0000x reference)
//
#include <hip/hip_runtime.h>
#include <cmath>

#define EMBED   1024
#define EPB     8
#define NB      64
#define KTOP    2
#define TPB_TOK 16          // tokens per block in binned main kernel
#define PW      4           // tokens per wave (TPB_TOK / 4 waves)
#define MAIN_BLOCKS 1280

// ---------------------------------------------------------------------------
// Kernel 1: reciprocal L2 norms of the 512 expert-key rows.
// One wave per row. Block 0 additionally zeroes the bucket counters so the
// histogram kernel can run next on the same stream (count may be nullptr on
// the fallback path).
// ---------------------------------------------------------------------------
__global__ void key_rnorm_kernel(const float* __restrict__ ek,
                                 float* __restrict__ rnorm,
                                 int* __restrict__ count, int nrows) {
    if (count != nullptr && blockIdx.x == 0 && threadIdx.x < NB)
        count[threadIdx.x] = 0;
    int wave = (int)((blockIdx.x * blockDim.x + threadIdx.x) >> 6);
    int lane = threadIdx.x & 63;
    if (wave >= nrows) return;
    const float4* row = (const float4*)(ek + (size_t)wave * EMBED);
    float s = 0.f;
#pragma unroll
    for (int c = 0; c < 4; ++c) {
        float4 v = row[c * 64 + lane];
        s += v.x * v.x + v.y * v.y + v.z * v.z + v.w * v.w;
    }
#pragma unroll
    for (int off = 32; off; off >>= 1) s += __shfl_xor(s, off, 64);
    if (lane == 0) rnorm[wave] = 1.0f / fmaxf(sqrtf(s), 1e-12f);
}

// ---------------------------------------------------------------------------
// Binning pass A: per-bucket token histogram (LDS pre-aggregation).
// ---------------------------------------------------------------------------
__global__ void hist_kernel(const int* __restrict__ op, int ntok,
                            int* __restrict__ count) {
    __shared__ int hc[NB];
    int tid = threadIdx.x;
    if (tid < NB) hc[tid] = 0;
    __syncthreads();
    for (int i = blockIdx.x * blockDim.x + tid; i < ntok;
         i += gridDim.x * blockDim.x) {
        int b = op[i];
        b = min(max(b, 0), NB - 1);
        atomicAdd(&hc[b], 1);
    }
    __syncthreads();
    if (tid < NB && hc[tid]) atomicAdd(&count[tid], hc[tid]);
}

// ---------------------------------------------------------------------------
// Binning pass B: serial 64-entry scans (bucket starts, scatter cursors,
// chunk prefix). 64 iterations on one thread -- negligible.
// ---------------------------------------------------------------------------
__global__ void scan_kernel(const int* __restrict__ count,
                            int* __restrict__ bstart,
                            int* __restrict__ soffs,
                            int* __restrict__ cpre) {
    if (threadIdx.x == 0 && blockIdx.x == 0) {
        int acc = 0, cacc = 0;
        for (int b = 0; b < NB; ++b) {
            bstart[b] = acc;
            soffs[b]  = acc;
            cpre[b]   = cacc;
            acc  += count[b];
            cacc += (count[b] + TPB_TOK - 1) / TPB_TOK;
        }
        cpre[NB] = cacc;
    }
}

// ---------------------------------------------------------------------------
// Binning pass C: scatter token indices into bucket-major perm[].
// Order within a bucket is nondeterministic (atomic append) -- irrelevant,
// outputs are indexed by token id.
// ---------------------------------------------------------------------------
__global__ void scatter_kernel(const int* __restrict__ op, int ntok,
                               int* __restrict__ soffs,
                               int* __restrict__ perm) {
    for (int i = blockIdx.x * blockDim.x + threadIdx.x; i < ntok;
         i += gridDim.x * blockDim.x) {
        int b = op[i];
        b = min(max(b, 0), NB - 1);
        int pos = atomicAdd(&soffs[b], 1);
        perm[pos] = i;
    }
}

// ---------------------------------------------------------------------------
// Main binned kernel: grid-stride over chunks of TPB_TOK same-bucket tokens.
// Each block stages its bucket's 8 keys (32 KB) in LDS once, then each of the
// 4 waves processes PW=4 tokens. Per-token math is bitwise identical to the
// verified one-wave-per-token kernel (same FMA expressions, same butterfly
// order, same tie-break) so numerics match exactly.
// ---------------------------------------------------------------------------
__global__ __launch_bounds__(256) void router_binned_kernel(
    const float* __restrict__ h,  const float* __restrict__ ek,
    const float* __restrict__ rk, const int* __restrict__ perm,
    const int* __restrict__ count, const int* __restrict__ bstart,
    const int* __restrict__ cpre,
    float* __restrict__ out_gid, float* __restrict__ out_w) {
    __shared__ float4 sk[EPB * EMBED / 4];   // 2048 float4 = 32 KB
    __shared__ float  s_rk[EPB];
    __shared__ int    s_cpre[NB + 1];
    __shared__ int    s_bs[NB];
    __shared__ int    s_cnt[NB];

    int tid = threadIdx.x;
    if (tid < NB + 1) s_cpre[tid] = cpre[tid];
    if (tid < NB) { s_bs[tid] = bstart[tid]; s_cnt[tid] = count[tid]; }
    __syncthreads();

    int total = s_cpre[NB];
    int w = tid >> 6, lane = tid & 63;

    for (int g = blockIdx.x; g < total; g += gridDim.x) {
        // chunk -> (bucket, local chunk): uniform LDS search, <=64 iters
        int b = 0;
        while (s_cpre[b + 1] <= g) ++b;
        int lc = g - s_cpre[b];

        __syncthreads();   // previous iteration's LDS reads complete
        const float4* src = (const float4*)(ek + (size_t)b * EPB * EMBED);
#pragma unroll
        for (int i = 0; i < 8; ++i) sk[i * 256 + tid] = src[i * 256 + tid];
        if (tid < EPB) s_rk[tid] = rk[b * EPB + tid];
        __syncthreads();

        int base = s_bs[b] + lc * TPB_TOK + w * PW;
        int end  = s_bs[b] + s_cnt[b];
        int tok[PW];
#pragma unroll
        for (int t = 0; t < PW; ++t) {
            int gi = base + t;
            tok[t] = perm[min(gi, end - 1)];   // clamp: dummy = valid token
        }

#pragma unroll
        for (int t = 0; t < PW; ++t) {
            const float4* hrow = (const float4*)(h + (size_t)tok[t] * EMBED);
            float4 hv[4];
            float hh = 0.f;
#pragma unroll
            for (int c = 0; c < 4; ++c) {
                hv[c] = hrow[c * 64 + lane];
                hh += hv[c].x * hv[c].x + hv[c].y * hv[c].y +
                      hv[c].z * hv[c].z + hv[c].w * hv[c].w;
            }
            float dot[EPB];
#pragma unroll
            for (int e = 0; e < EPB; ++e) {
                float d = 0.f;
#pragma unroll
                for (int c = 0; c < 4; ++c) {
                    float4 kv = sk[e * 256 + c * 64 + lane];
                    d += hv[c].x * kv.x + hv[c].y * kv.y +
                         hv[c].z * kv.z + hv[c].w * kv.w;
                }
                dot[e] = d;
            }
#pragma unroll
            for (int off = 32; off; off >>= 1) {
                hh += __shfl_xor(hh, off, 64);
#pragma unroll
                for (int e = 0; e < EPB; ++e)
                    dot[e] += __shfl_xor(dot[e], off, 64);
            }
            if (lane == 0 && (base + t) < end) {
                float rh = 1.0f / fmaxf(sqrtf(hh), 1e-12f);
                float sc[EPB];
                float m = -1e30f;
#pragma unroll
                for (int e = 0; e < EPB; ++e) {
                    sc[e] = dot[e] * rh * s_rk[e];   // TAU = 1.0
                    m = fmaxf(m, sc[e]);
                }
                float ex[EPB];
                float Z = 0.f;
#pragma unroll
                for (int e = 0; e < EPB; ++e) { ex[e] = expf(sc[e] - m); Z += ex[e]; }
                int i1 = 0;
#pragma unroll
                for (int e = 1; e < EPB; ++e) if (ex[e] > ex[i1]) i1 = e;
                int i2 = (i1 == 0) ? 1 : 0;
#pragma unroll
                for (int e = 0; e < EPB; ++e)
                    if (e != i1 && ex[e] > ex[i2]) i2 = e;
                float p1 = ex[i1] / Z;
                float p2 = ex[i2] / Z;
                float wsum = p1 + p2 + 1e-9f;
                int tk = tok[t];
                out_gid[(size_t)tk * KTOP + 0] = (float)(b * EPB + i1);
                out_gid[(size_t)tk * KTOP + 1] = (float)(b * EPB + i2);
                out_w  [(size_t)tk * KTOP + 0] = p1 / wsum;
                out_w  [(size_t)tk * KTOP + 1] = p2 / wsum;
            }
        }
    }
}

// ---------------------------------------------------------------------------
// Fallback: the previous verified one-wave-per-token kernel (used only if the
// workspace can't hold the binning state).
// ---------------------------------------------------------------------------
__global__ void router_kernel(const float* __restrict__ h,
                              const int*   __restrict__ op_id,
                              const float* __restrict__ ek,
                              const float* __restrict__ rk,
                              float* __restrict__ out_gid,
                              float* __restrict__ out_w,
                              int ntok) {
    int wave = (int)((blockIdx.x * blockDim.x + threadIdx.x) >> 6);
    int lane = threadIdx.x & 63;
    if (wave >= ntok) return;

    int b = op_id[wave];
    b = min(max(b, 0), NB - 1);

    const float4* hrow = (const float4*)(h + (size_t)wave * EMBED);
    float4 hv[4];
    float hh = 0.f;
#pragma unroll
    for (int c = 0; c < 4; ++c) {
        hv[c] = hrow[c * 64 + lane];
        hh += hv[c].x * hv[c].x + hv[c].y * hv[c].y +
              hv[c].z * hv[c].z + hv[c].w * hv[c].w;
    }
    const float4* kbase = (const float4*)(ek + (size_t)b * EPB * EMBED);
    float dot[EPB];
#pragma unroll
    for (int e = 0; e < EPB; ++e) {
        float d = 0.f;
#pragma unroll
        for (int c = 0; c < 4; ++c) {
            float4 kv = kbase[e * 256 + c * 64 + lane];
            d += hv[c].x * kv.x + hv[c].y * kv.y +
                 hv[c].z * kv.z + hv[c].w * kv.w;
        }
        dot[e] = d;
    }
#pragma unroll
    for (int off = 32; off; off >>= 1) {
        hh += __shfl_xor(hh, off, 64);
#pragma unroll
        for (int e = 0; e < EPB; ++e) dot[e] += __shfl_xor(dot[e], off, 64);
    }
    if (lane == 0) {
        float rh = 1.0f / fmaxf(sqrtf(hh), 1e-12f);
        float sc[EPB];
        float m = -1e30f;
#pragma unroll
        for (int e = 0; e < EPB; ++e) {
            sc[e] = dot[e] * rh * rk[b * EPB + e];
            m = fmaxf(m, sc[e]);
        }
        float ex[EPB];
        float Z = 0.f;
#pragma unroll
        for (int e = 0; e < EPB; ++e) { ex[e] = expf(sc[e] - m); Z += ex[e]; }
        int i1 = 0;
#pragma unroll
        for (int e = 1; e < EPB; ++e) if (ex[e] > ex[i1]) i1 = e;
        int i2 = (i1 == 0) ? 1 : 0;
#pragma unroll
        for (int e = 0; e < EPB; ++e)
            if (e != i1 && ex[e] > ex[i2]) i2 = e;
        float p1 = ex[i1] / Z;
        float p2 = ex[i2] / Z;
        float wsum = p1 + p2 + 1e-9f;
        out_gid[(size_t)wave * KTOP + 0] = (float)(b * EPB + i1);
        out_gid[(size_t)wave * KTOP + 1] = (float)(b * EPB + i2);
        out_w  [(size_t)wave * KTOP + 0] = p1 / wsum;
        out_w  [(size_t)wave * KTOP + 1] = p2 / wsum;
    }
}

extern "C" void kernel_launch(void* const* d_in, const int* in_sizes, int n_in,
                              void* d_out, int out_size, void* d_ws, size_t ws_size,
                              hipStream_t stream) {
    const float* h     = (const float*)d_in[0];
    const int*   op_id = (const int*)  d_in[1];
    const float* ek    = (const float*)d_in[2];

    int ntok  = in_sizes[1];           // B*T tokens
    int nrows = NB * EPB;              // 512 key rows

    float* out_gid = (float*)d_out;
    float* out_w   = out_gid + (size_t)ntok * KTOP;

    // Workspace layout (all 4-byte typed):
    //   rk[512] | count[64] | bstart[64] | soffs[64] | cpre[65] | perm[ntok]
    float* rk     = (float*)d_ws;
    int*   count  = (int*)(rk + 512);
    int*   bstart = count  + NB;
    int*   soffs  = bstart + NB;
    int*   cpre   = soffs  + NB;
    int*   perm   = cpre   + (NB + 1);
    size_t need   = ((size_t)(512 + 3 * NB + NB + 1) + (size_t)ntok) * 4;

    int blocks1 = (nrows * 64 + 255) / 256;

    if (ws_size < need) {
        // Fallback: previous verified path.
        key_rnorm_kernel<<<blocks1, 256, 0, stream>>>(ek, rk, nullptr, nrows);
        int blocks2 = (ntok * 64 + 255) / 256;
        router_kernel<<<blocks2, 256, 0, stream>>>(h, op_id, ek, rk,
                                                   out_gid, out_w, ntok);
        return;
    }

    // A: key rnorms + zero bucket counters
    key_rnorm_kernel<<<blocks1, 256, 0, stream>>>(ek, rk, count, nrows);
    // B: histogram
    hist_kernel<<<64, 256, 0, stream>>>(op_id, ntok, count);
    // C: scans
    scan_kernel<<<1, 64, 0, stream>>>(count, bstart, soffs, cpre);
    // D: scatter into bucket-major perm
    scatter_kernel<<<64, 256, 0, stream>>>(op_id, ntok, soffs, perm);
    // E: binned main kernel
    router_binned_kernel<<<MAIN_BLOCKS, 256, 0, stream>>>(
        h, ek, rk, perm, count, bstart, cpre, out_gid, out_w);
}

// Round 2
// 137.219 us; speedup vs baseline: 1.1607x; 1.1607x over previous
//
#include <hip/hip_runtime.h>
#include <cmath>

#define EMBED   1024
#define EPB     8
#define NB      64
#define KTOP    2
#define TPB_TOK 32              // tokens per chunk in main kernel
#define KPAD    1028            // key row stride in LDS floats (bank-quad spread)

// ---------------------------------------------------------------------------
// Fused prep kernel, 33 blocks x 1024 threads:
//   blocks 0..31 : reciprocal L2 norms of the 512 expert-key rows (16 waves ea)
//   block 32     : full binning in one block: LDS histogram -> wave-0 shuffle
//                  scan -> LDS-cursor scatter into bucket-major perm[], plus
//                  chunk->bucket map. No global atomics, no serial scan.
// ---------------------------------------------------------------------------
__global__ __launch_bounds__(1024) void prep_kernel(
    const float* __restrict__ ek, float* __restrict__ rnorm,
    const int* __restrict__ op, int ntok,
    int* __restrict__ bstart_g, int* __restrict__ cnt_g,
    int* __restrict__ cpre_g, int* __restrict__ chunk2b,
    int* __restrict__ perm) {
    int tid  = threadIdx.x;
    int lane = tid & 63;
    int wave = tid >> 6;

    if (blockIdx.x < 32) {
        // ---- key rnorm: one wave per row ----
        int row = blockIdx.x * 16 + wave;          // < 512 always
        const float4* r4 = (const float4*)(ek + (size_t)row * EMBED);
        float s = 0.f;
#pragma unroll
        for (int c = 0; c < 4; ++c) {
            float4 v = r4[c * 64 + lane];
            s += v.x * v.x + v.y * v.y + v.z * v.z + v.w * v.w;
        }
#pragma unroll
        for (int off = 32; off; off >>= 1) s += __shfl_xor(s, off, 64);
        if (lane == 0) rnorm[row] = 1.0f / fmaxf(sqrtf(s), 1e-12f);
        return;
    }

    // ---- binning block ----
    __shared__ int s_hist[NB];
    __shared__ int s_cur[NB];
    if (tid < NB) s_hist[tid] = 0;
    __syncthreads();
    for (int i = tid; i < ntok; i += 1024) {
        int b = min(max(op[i], 0), NB - 1);
        atomicAdd(&s_hist[b], 1);
    }
    __syncthreads();
    if (tid < 64) {                                // wave 0 exactly
        int c   = s_hist[tid];
        int nch = (c + TPB_TOK - 1) / TPB_TOK;
        int ic = c, in = nch;                      // inclusive scans
#pragma unroll
        for (int off = 1; off < 64; off <<= 1) {
            int vc = __shfl_up(ic, off, 64);
            int vn = __shfl_up(in, off, 64);
            if (lane >= off) { ic += vc; in += vn; }
        }
        int bs = ic - c;                           // exclusive
        int cp = in - nch;
        s_cur[tid]    = bs;
        bstart_g[tid] = bs;
        cnt_g[tid]    = c;
        cpre_g[tid]   = cp;
        if (tid == 63) cpre_g[NB] = in;            // total chunks
        for (int j = 0; j < nch; ++j) chunk2b[cp + j] = tid;
    }
    __syncthreads();
    for (int i = tid; i < ntok; i += 1024) {
        int b = min(max(op[i], 0), NB - 1);
        int pos = atomicAdd(&s_cur[b], 1);
        perm[pos] = i;
    }
}

// ---------------------------------------------------------------------------
// Main kernel: grid-stride over chunks of TPB_TOK=32 same-bucket tokens.
// 256 threads = 4 waves; wave = 8 token-groups x 8 experts. Each LANE owns
// one full (token, expert) 1024-element dot -> zero cross-lane reduction for
// the dots; ||h||^2 computed redundantly per expert lane (same broadcast
// data, free). Softmax + top-2 run on 8-lane groups: ~18 shuffle instrs per
// wave cover all 8 tokens simultaneously (vs 54 per token before).
// Keys staged once per chunk into LDS with row stride 1028 floats so the 8
// expert rows occupy distinct bank quads (conflict-free ds_read_b128).
// ---------------------------------------------------------------------------
__global__ __launch_bounds__(256) void router_main_kernel(
    const float* __restrict__ h,  const float* __restrict__ ek,
    const float* __restrict__ rk, const int* __restrict__ perm,
    const int* __restrict__ bstart_g, const int* __restrict__ cnt_g,
    const int* __restrict__ cpre_g, const int* __restrict__ chunk2b,
    float* __restrict__ out_gid, float* __restrict__ out_w) {
    __shared__ float sk[EPB * KPAD];               // 32.9 KB
    __shared__ float s_rk[EPB];

    int tid  = threadIdx.x;
    int lane = tid & 63;
    int wave = tid >> 6;
    int grp  = lane >> 3;                          // token group 0..7
    int e    = lane & 7;                           // expert 0..7
    int ts   = wave * 8 + grp;                     // token slot 0..31

    int total = cpre_g[NB];

    for (int g = blockIdx.x; g < total; g += gridDim.x) {
        int b  = chunk2b[g];
        int lc = g - cpre_g[b];

        __syncthreads();                           // protect LDS reuse
        const float4* src4 = (const float4*)ek + (size_t)b * (EPB * EMBED / 4);
#pragma unroll
        for (int k = 0; k < 8; ++k) {
            int idx = k * 256 + tid;               // 0..2047
            int r = idx >> 8, c = idx & 255;
            *(float4*)(sk + r * KPAD + c * 4) = src4[idx];
        }
        if (tid < EPB) s_rk[tid] = rk[b * EPB + tid];
        __syncthreads();

        int base = bstart_g[b] + lc * TPB_TOK;
        int end  = bstart_g[b] + cnt_g[b];
        int gi   = base + ts;
        int tok  = perm[min(gi, end - 1)];         // clamp: dummy = valid tok

        const float4* hrow = (const float4*)(h + (size_t)tok * EMBED);
        const float*  kp   = sk + e * KPAD;

        float dot = 0.f, hh = 0.f;
#pragma unroll 8
        for (int c = 0; c < 256; ++c) {
            float4 a  = hrow[c];
            float4 kv = *(const float4*)(kp + c * 4);
            dot += a.x * kv.x + a.y * kv.y + a.z * kv.z + a.w * kv.w;
            hh  += a.x * a.x + a.y * a.y + a.z * a.z + a.w * a.w;
        }

        // ---- 8-lane-group softmax + top-2 (all 8 tokens of wave at once) ---
        float rh = 1.0f / fmaxf(sqrtf(hh), 1e-12f);
        float sc = dot * rh * s_rk[e];             // TAU = 1.0

        float m = sc;
#pragma unroll
        for (int off = 1; off < 8; off <<= 1)
            m = fmaxf(m, __shfl_xor(m, off, 64));
        float ex = expf(sc - m);
        float Z = ex;
#pragma unroll
        for (int off = 1; off < 8; off <<= 1)
            Z += __shfl_xor(Z, off, 64);

        // top-1 (lowest index wins ties)
        float v1 = ex; int i1 = e;
#pragma unroll
        for (int off = 1; off < 8; off <<= 1) {
            float ov = __shfl_xor(v1, off, 64);
            int   oi = __shfl_xor(i1, off, 64);
            if (ov > v1 || (ov == v1 && oi < i1)) { v1 = ov; i1 = oi; }
        }
        // top-2: exclude i1
        float v2 = (e == i1) ? -1e30f : ex; int i2 = e;
#pragma unroll
        for (int off = 1; off < 8; off <<= 1) {
            float ov = __shfl_xor(v2, off, 64);
            int   oi = __shfl_xor(i2, off, 64);
            if (ov > v2 || (ov == v2 && oi < i2)) { v2 = ov; i2 = oi; }
        }

        if (e == 0 && gi < end) {
            float p1 = v1 / Z, p2 = v2 / Z;
            float ws = p1 + p2 + 1e-9f;
            ((float2*)out_gid)[tok] =
                make_float2((float)(b * EPB + i1), (float)(b * EPB + i2));
            ((float2*)out_w)[tok] = make_float2(p1 / ws, p2 / ws);
        }
    }
}

// ---------------------------------------------------------------------------
// Fallback path (workspace too small): previous verified 2-kernel version.
// ---------------------------------------------------------------------------
__global__ void key_rnorm_kernel(const float* __restrict__ ek,
                                 float* __restrict__ rnorm, int nrows) {
    int wave = (int)((blockIdx.x * blockDim.x + threadIdx.x) >> 6);
    int lane = threadIdx.x & 63;
    if (wave >= nrows) return;
    const float4* row = (const float4*)(ek + (size_t)wave * EMBED);
    float s = 0.f;
#pragma unroll
    for (int c = 0; c < 4; ++c) {
        float4 v = row[c * 64 + lane];
        s += v.x * v.x + v.y * v.y + v.z * v.z + v.w * v.w;
    }
#pragma unroll
    for (int off = 32; off; off >>= 1) s += __shfl_xor(s, off, 64);
    if (lane == 0) rnorm[wave] = 1.0f / fmaxf(sqrtf(s), 1e-12f);
}

__global__ void router_kernel(const float* __restrict__ h,
                              const int*   __restrict__ op_id,
                              const float* __restrict__ ek,
                              const float* __restrict__ rk,
                              float* __restrict__ out_gid,
                              float* __restrict__ out_w,
                              int ntok) {
    int wave = (int)((blockIdx.x * blockDim.x + threadIdx.x) >> 6);
    int lane = threadIdx.x & 63;
    if (wave >= ntok) return;
    int b = op_id[wave];
    b = min(max(b, 0), NB - 1);
    const float4* hrow = (const float4*)(h + (size_t)wave * EMBED);
    float4 hv[4];
    float hh = 0.f;
#pragma unroll
    for (int c = 0; c < 4; ++c) {
        hv[c] = hrow[c * 64 + lane];
        hh += hv[c].x * hv[c].x + hv[c].y * hv[c].y +
              hv[c].z * hv[c].z + hv[c].w * hv[c].w;
    }
    const float4* kbase = (const float4*)(ek + (size_t)b * EPB * EMBED);
    float dot[EPB];
#pragma unroll
    for (int e = 0; e < EPB; ++e) {
        float d = 0.f;
#pragma unroll
        for (int c = 0; c < 4; ++c) {
            float4 kv = kbase[e * 256 + c * 64 + lane];
            d += hv[c].x * kv.x + hv[c].y * kv.y +
                 hv[c].z * kv.z + hv[c].w * kv.w;
        }
        dot[e] = d;
    }
#pragma unroll
    for (int off = 32; off; off >>= 1) {
        hh += __shfl_xor(hh, off, 64);
#pragma unroll
        for (int e = 0; e < EPB; ++e) dot[e] += __shfl_xor(dot[e], off, 64);
    }
    if (lane == 0) {
        float rh = 1.0f / fmaxf(sqrtf(hh), 1e-12f);
        float sc[EPB];
        float m = -1e30f;
#pragma unroll
        for (int e = 0; e < EPB; ++e) {
            sc[e] = dot[e] * rh * rk[b * EPB + e];
            m = fmaxf(m, sc[e]);
        }
        float ex[EPB];
        float Z = 0.f;
#pragma unroll
        for (int e = 0; e < EPB; ++e) { ex[e] = expf(sc[e] - m); Z += ex[e]; }
        int i1 = 0;
#pragma unroll
        for (int e = 1; e < EPB; ++e) if (ex[e] > ex[i1]) i1 = e;
        int i2 = (i1 == 0) ? 1 : 0;
#pragma unroll
        for (int e = 0; e < EPB; ++e)
            if (e != i1 && ex[e] > ex[i2]) i2 = e;
        float p1 = ex[i1] / Z;
        float p2 = ex[i2] / Z;
        float wsum = p1 + p2 + 1e-9f;
        out_gid[(size_t)wave * KTOP + 0] = (float)(b * EPB + i1);
        out_gid[(size_t)wave * KTOP + 1] = (float)(b * EPB + i2);
        out_w  [(size_t)wave * KTOP + 0] = p1 / wsum;
        out_w  [(size_t)wave * KTOP + 1] = p2 / wsum;
    }
}

extern "C" void kernel_launch(void* const* d_in, const int* in_sizes, int n_in,
                              void* d_out, int out_size, void* d_ws, size_t ws_size,
                              hipStream_t stream) {
    const float* h     = (const float*)d_in[0];
    const int*   op_id = (const int*)  d_in[1];
    const float* ek    = (const float*)d_in[2];

    int ntok = in_sizes[1];                    // B*T tokens
    int maxch = NB + (ntok + TPB_TOK - 1) / TPB_TOK;

    float* out_gid = (float*)d_out;
    float* out_w   = out_gid + (size_t)ntok * KTOP;

    // Workspace: rk[512] | bstart[64] | cnt[64] | cpre[65] | chunk2b | perm
    float* rk      = (float*)d_ws;
    int*   bstart  = (int*)(rk + 512);
    int*   cnt     = bstart + NB;
    int*   cpre    = cnt + NB;
    int*   chunk2b = cpre + (NB + 1);
    int*   perm    = chunk2b + maxch;
    size_t need    = ((size_t)(512 + 2 * NB + NB + 1 + maxch) + (size_t)ntok) * 4;

    if (ws_size < need) {
        key_rnorm_kernel<<<128, 256, 0, stream>>>(ek, rk, NB * EPB);
        int blocks2 = (ntok * 64 + 255) / 256;
        router_kernel<<<blocks2, 256, 0, stream>>>(h, op_id, ek, rk,
                                                   out_gid, out_w, ntok);
        return;
    }

    // 1: fused rnorm (blocks 0..31) + binning (block 32)
    prep_kernel<<<33, 1024, 0, stream>>>(ek, rk, op_id, ntok,
                                         bstart, cnt, cpre, chunk2b, perm);
    // 2: main binned router
    router_main_kernel<<<maxch, 256, 0, stream>>>(
        h, ek, rk, perm, bstart, cnt, cpre, chunk2b, out_gid, out_w);
}

// Round 3
// 115.947 us; speedup vs baseline: 1.3736x; 1.1835x over previous
//
#include <hip/hip_runtime.h>
#include <cmath>

#define EMBED   1024
#define EPB     8
#define NB      64
#define KTOP    2

// ---------------------------------------------------------------------------
// Kernel 1: reciprocal L2 norms of the 512 expert-key rows.
// One wave per row; verified pattern from previous rounds.
// ---------------------------------------------------------------------------
__global__ void key_rnorm_kernel(const float* __restrict__ ek,
                                 float* __restrict__ rnorm) {
    int wave = (int)((blockIdx.x * blockDim.x + threadIdx.x) >> 6);
    int lane = threadIdx.x & 63;
    if (wave >= NB * EPB) return;
    const float4* row = (const float4*)(ek + (size_t)wave * EMBED);
    float s = 0.f;
#pragma unroll
    for (int c = 0; c < 4; ++c) {
        float4 v = row[c * 64 + lane];
        s += v.x * v.x + v.y * v.y + v.z * v.z + v.w * v.w;
    }
#pragma unroll
    for (int off = 32; off; off >>= 1) s += __shfl_xor(s, off, 64);
    if (lane == 0) rnorm[wave] = 1.0f / fmaxf(sqrtf(s), 1e-12f);
}

// ---------------------------------------------------------------------------
// Main kernel: one wave = 4 tokens, 16 lanes per token.
//   - lane (q = lane>>4, r = lane&15) holds 16 float4 of token q's h-row:
//     4 load insts per token, each touching only 8 cache lines (vs 256
//     line-touches/token in the previous layout).
//   - keys read directly from L2 (2 MB key set is L2-resident; no LDS, no
//     binning): per (e,i) instruction the 4 quarters fetch 4x256 B
//     contiguous segments -> 1 KB distinct bytes per b128 instruction.
//   - dots + ||h||^2 reduced with a 4-stage __shfl_xor butterfly (offsets
//     8,4,2,1 stay inside the 16-lane quarter): 36 shuffles per 4 tokens.
//   - softmax + top-2 computed redundantly by all 16 lanes (uniform, no
//     divergence); lane r==0 writes the float2 outputs.
// No LDS -> occupancy VGPR-bound; launch_bounds(256,4) pins <=128 VGPR
// (live peak ~110) giving 16 waves/CU.
// ---------------------------------------------------------------------------
__global__ __launch_bounds__(256, 4) void router_quad_kernel(
    const float* __restrict__ h, const int* __restrict__ op,
    const float* __restrict__ ek, const float* __restrict__ rk,
    float* __restrict__ out_gid, float* __restrict__ out_w, int ntok) {
    int gtid = blockIdx.x * blockDim.x + threadIdx.x;
    int wid  = gtid >> 6;                      // global wave id
    int lane = threadIdx.x & 63;
    int q    = lane >> 4;                      // token quarter 0..3
    int r    = lane & 15;                      // lane within quarter
    int tq   = wid * 4 + q;                    // token id
    int tc   = min(tq, ntok - 1);              // clamped (dummy = valid tok)

    int b = op[tc];
    b = min(max(b, 0), NB - 1);

    // ---- h fragment: 16 float4 per lane, coalesced per 16-lane quarter ----
    const float4* hrow = (const float4*)(h + (size_t)tc * EMBED);
    float4 hv[16];
    float hh = 0.f;
#pragma unroll
    for (int i = 0; i < 16; ++i) {
        hv[i] = hrow[i * 16 + r];
        hh += hv[i].x * hv[i].x + hv[i].y * hv[i].y +
              hv[i].z * hv[i].z + hv[i].w * hv[i].w;
    }

    float rke[EPB];
#pragma unroll
    for (int e = 0; e < EPB; ++e) rke[e] = rk[b * EPB + e];

    // ---- 8 dots, keys streamed from L2 ----
    const float4* kb = (const float4*)ek + (size_t)b * (EPB * EMBED / 4);
    float dot[EPB];
#pragma unroll
    for (int e = 0; e < EPB; ++e) {
        float d = 0.f;
#pragma unroll
        for (int i = 0; i < 16; ++i) {
            float4 kv = kb[e * 256 + i * 16 + r];
            d += hv[i].x * kv.x + hv[i].y * kv.y +
                 hv[i].z * kv.z + hv[i].w * kv.w;
        }
        dot[e] = d;
    }

    // ---- 4-stage butterfly within each 16-lane quarter ----
#pragma unroll
    for (int off = 8; off; off >>= 1) {
        hh += __shfl_xor(hh, off, 64);         // off<16 never leaves quarter
#pragma unroll
        for (int e = 0; e < EPB; ++e) dot[e] += __shfl_xor(dot[e], off, 64);
    }

    // ---- softmax + top-2, redundant on all 16 lanes (uniform) ----
    float rh = 1.0f / fmaxf(sqrtf(hh), 1e-12f);
    float sc[EPB];
    float m = -1e30f;
#pragma unroll
    for (int e = 0; e < EPB; ++e) {
        sc[e] = dot[e] * rh * rke[e];          // TAU = 1.0
        m = fmaxf(m, sc[e]);
    }
    float ex[EPB];
    float Z = 0.f;
#pragma unroll
    for (int e = 0; e < EPB; ++e) { ex[e] = expf(sc[e] - m); Z += ex[e]; }

    int i1 = 0;                                 // top-1, lowest index on ties
#pragma unroll
    for (int e = 1; e < EPB; ++e) if (ex[e] > ex[i1]) i1 = e;
    int i2 = (i1 == 0) ? 1 : 0;                 // top-2 excluding i1
#pragma unroll
    for (int e = 0; e < EPB; ++e)
        if (e != i1 && ex[e] > ex[i2]) i2 = e;

    if (r == 0 && tq < ntok) {
        float p1 = ex[i1] / Z;
        float p2 = ex[i2] / Z;
        float ws = p1 + p2 + 1e-9f;
        ((float2*)out_gid)[tq] =
            make_float2((float)(b * EPB + i1), (float)(b * EPB + i2));
        ((float2*)out_w)[tq] = make_float2(p1 / ws, p2 / ws);
    }
}

extern "C" void kernel_launch(void* const* d_in, const int* in_sizes, int n_in,
                              void* d_out, int out_size, void* d_ws, size_t ws_size,
                              hipStream_t stream) {
    const float* h     = (const float*)d_in[0];
    const int*   op_id = (const int*)  d_in[1];
    const float* ek    = (const float*)d_in[2];

    int ntok = in_sizes[1];                    // B*T tokens

    float* rk      = (float*)d_ws;             // 512 floats of scratch
    float* out_gid = (float*)d_out;
    float* out_w   = out_gid + (size_t)ntok * KTOP;

    // Kernel 1: 512 waves = 128 blocks of 256.
    key_rnorm_kernel<<<128, 256, 0, stream>>>(ek, rk);

    // Kernel 2: 4 tokens per wave, 16 tokens per 256-thread block.
    int blocks = (ntok + 15) / 16;
    router_quad_kernel<<<blocks, 256, 0, stream>>>(h, op_id, ek, rk,
                                                   out_gid, out_w, ntok);
}